// Round 12
// baseline (636.871 us; speedup 1.0000x reference)
//
#include <hip/hip_runtime.h>
#include <stdint.h>

// ---------------------------------------------------------------------------
// Problem constants: B=32, S=256, HID=1024, HEADS=16, DK=64, CLUE(runtime)=64
// ---------------------------------------------------------------------------
typedef __bf16 bf16_t;
typedef bf16_t bf16x8 __attribute__((ext_vector_type(8)));
typedef float f32x4 __attribute__((ext_vector_type(4)));

__device__ __forceinline__ unsigned short f2bf(float f) {
  __bf16 h = (__bf16)f;            // RNE, compiles to v_cvt (m240: don't hand-write)
  unsigned short u;
  __builtin_memcpy(&u, &h, 2);
  return u;
}

__device__ __forceinline__ void gload16(const unsigned short* g, unsigned short* l) {
  auto gp = (const __attribute__((address_space(1))) unsigned short*)(g);
  auto lp = (__attribute__((address_space(3))) unsigned short*)(l);
  __builtin_amdgcn_global_load_lds(gp, lp, 16, 0, 0);   // 16B/lane, dest = base + lane*16
}

// d(i,j): |i-j| when i,j on the same side of clue, else 1  (fp matrix of ref)
__device__ __forceinline__ int relidx(int i, int j, int clue) {
  return ((i >= clue) == (j >= clue)) ? (i > j ? i - j : j - i) : 1;
}

// ---------------------------------------------------------------------------
// prep kernel — blockIdx partition:
//   [0,4096):      embedding output = emb[d(i,j)] broadcast to [B,H,S,S]
//   [4096,7168):   q/k/v f32 -> bf16 (1024 blocks each)
//   [7168,11264):  Wq/Wk/Wv/Wo [K][N] f32 -> WT [N][K] bf16 (1024 blocks each)
// ---------------------------------------------------------------------------
__global__ __launch_bounds__(256) void prep_kernel(
    const float* __restrict__ q, const float* __restrict__ k, const float* __restrict__ v,
    const float* __restrict__ Wq, const float* __restrict__ Wk,
    const float* __restrict__ Wv, const float* __restrict__ Wo,
    const float* __restrict__ emb, const int* __restrict__ cluep,
    float* __restrict__ embo, unsigned short* __restrict__ qkvb,
    unsigned short* __restrict__ WT) {
  __shared__ float tile[32][33];
  const int bid = blockIdx.x, tid = threadIdx.x;

  if (bid < 4096) {
    const int clue = cluep[0];
    float4* o4 = reinterpret_cast<float4*>(embo);
    #pragma unroll
    for (int it = 0; it < 8; ++it) {
      const int i4 = bid * 2048 + it * 256 + tid;
      const int fpos = (i4 & 16383) * 4;       // position within one [S,S] tile
      const int i = fpos >> 8, j0 = fpos & 255;
      float4 r;
      r.x = emb[relidx(i, j0 + 0, clue)];
      r.y = emb[relidx(i, j0 + 1, clue)];
      r.z = emb[relidx(i, j0 + 2, clue)];
      r.w = emb[relidx(i, j0 + 3, clue)];
      o4[i4] = r;
    }
  } else if (bid < 7168) {
    const int local = bid - 4096;
    const int which = local >> 10, lb = local & 1023;
    const float* in_ = which == 0 ? q : which == 1 ? k : v;
    unsigned short* out_ = qkvb + (size_t)which * 8388608;
    for (int i = lb * 256 + tid; i < 1048576; i += 262144) {   // 8 elems/iter
      float4 a = reinterpret_cast<const float4*>(in_)[2 * i];
      float4 b = reinterpret_cast<const float4*>(in_)[2 * i + 1];
      ushort4 p, qq;
      p.x = f2bf(a.x); p.y = f2bf(a.y); p.z = f2bf(a.z); p.w = f2bf(a.w);
      qq.x = f2bf(b.x); qq.y = f2bf(b.y); qq.z = f2bf(b.z); qq.w = f2bf(b.w);
      reinterpret_cast<ushort4*>(out_)[2 * i] = p;
      reinterpret_cast<ushort4*>(out_)[2 * i + 1] = qq;
    }
  } else {
    const int local = bid - 7168;
    const int which = local >> 10, wl = local & 1023;
    const float* in_ = which == 0 ? Wq : which == 1 ? Wk : which == 2 ? Wv : Wo;
    unsigned short* out_ = WT + (size_t)which * 2097152;
    const int tx = tid & 31, ty = tid >> 5;
    const int k0 = (wl & 31) * 32, n0 = (wl >> 5) * 32;
    #pragma unroll
    for (int p = 0; p < 4; ++p)
      tile[ty + p * 8][tx] = in_[(size_t)(k0 + ty + p * 8) * 1024 + n0 + tx];
    __syncthreads();
    #pragma unroll
    for (int p = 0; p < 4; ++p)
      out_[(size_t)(n0 + ty + p * 8) * 1024 + k0 + tx] = f2bf(tile[tx][ty + p * 8]);
  }
}

// ---------------------------------------------------------------------------
// GEMM: C[8192][1024] = A(bf16) @ BT^T + bvec.  128x128 tile, BK=64, 4 waves,
// mfma_f32_16x16x32_bf16, global_load_lds(16) staging with pre-swizzled global
// source (linear LDS dest, XOR on read side — rule #21 both-sides).
// grid.z selects q/k/v slice (contiguous A/BT/C bases). mode==2: O-projection
// (f32 C). z==2 with mode==0: vhT[b,h,d,s] transposed epilogue.
// ---------------------------------------------------------------------------
constexpr int GK = 1024, GN = 1024;

__global__ __launch_bounds__(256, 3) void gemm_fused(
    const unsigned short* __restrict__ Abase, const unsigned short* __restrict__ BTbase,
    const float* __restrict__ b0, const float* __restrict__ b1, const float* __restrict__ b2,
    void* __restrict__ Cbase, int mode) {
  __shared__ unsigned short Alds[128 * 64];   // 16 KB, linear
  __shared__ unsigned short Blds[128 * 64];
  const int t = threadIdx.x;
  const int lane = t & 63;
  const int w = t >> 6;
  const int wr = (w >> 1) * 64;
  const int wc = (w & 1) * 64;
  const int m0 = blockIdx.y * 128;
  const int n0 = blockIdx.x * 128;
  const int zz = blockIdx.z;
  const int lg = lane >> 4;
  const int lr = lane & 15;

  const unsigned short* A  = Abase + (size_t)zz * 8388608;
  const unsigned short* BT = BTbase + (size_t)zz * 2097152;
  const float* bvec = zz == 0 ? b0 : zz == 1 ? b1 : b2;

  const int srow = w * 32 + (lane >> 3);            // + i*8
  const int gch  = (lane & 7) ^ ((lane >> 3) & 7);  // swizzled source chunk

  f32x4 acc[4][4] = {};

  for (int k0 = 0; k0 < GK; k0 += 64) {
    #pragma unroll
    for (int i = 0; i < 4; ++i) {
      gload16(A  + (size_t)(m0 + srow + i * 8) * GK + k0 + gch * 8,
              &Alds[(w * 32 + i * 8) * 64]);
      gload16(BT + (size_t)(n0 + srow + i * 8) * GK + k0 + gch * 8,
              &Blds[(w * 32 + i * 8) * 64]);
    }
    __syncthreads();
    #pragma unroll
    for (int ks = 0; ks < 2; ++ks) {
      bf16x8 af[4], bfr[4];
      #pragma unroll
      for (int m = 0; m < 4; ++m) {
        const int r = wr + m * 16 + lr;
        const int cc = (ks * 4 + lg) ^ (lr & 7);
        af[m] = *reinterpret_cast<const bf16x8*>(&Alds[r * 64 + cc * 8]);
      }
      #pragma unroll
      for (int n = 0; n < 4; ++n) {
        const int r = wc + n * 16 + lr;
        const int cc = (ks * 4 + lg) ^ (lr & 7);
        bfr[n] = *reinterpret_cast<const bf16x8*>(&Blds[r * 64 + cc * 8]);
      }
      __builtin_amdgcn_s_setprio(1);
      #pragma unroll
      for (int m = 0; m < 4; ++m) {
        #pragma unroll
        for (int n = 0; n < 4; ++n)
          acc[m][n] = __builtin_amdgcn_mfma_f32_16x16x32_bf16(af[m], bfr[n], acc[m][n], 0, 0, 0);
      }
      __builtin_amdgcn_s_setprio(0);
    }
    __syncthreads();
  }

  const int omode = (mode == 2) ? 2 : (zz == 2 ? 1 : 0);
  #pragma unroll
  for (int m = 0; m < 4; ++m) {
    #pragma unroll
    for (int n = 0; n < 4; ++n) {
      const int col = n0 + wc + n * 16 + lr;
      const float bv = bvec[col];
      const int rbase = m0 + wr + m * 16 + lg * 4;
      if (omode == 0) {
        unsigned short* C = (unsigned short*)Cbase + (size_t)zz * 8388608;
        #pragma unroll
        for (int j = 0; j < 4; ++j)
          C[(size_t)(rbase + j) * GN + col] = f2bf(acc[m][n][j] + bv);
      } else if (omode == 1) {
        unsigned short* C = (unsigned short*)Cbase + (size_t)zz * 8388608;  // vhT
        const int b = rbase >> 8, s = rbase & 255;
        const int h = col >> 6, d = col & 63;
        ushort4 pk;
        pk.x = f2bf(acc[m][n][0] + bv);
        pk.y = f2bf(acc[m][n][1] + bv);
        pk.z = f2bf(acc[m][n][2] + bv);
        pk.w = f2bf(acc[m][n][3] + bv);
        *reinterpret_cast<ushort4*>(&C[(size_t)((b * 16 + h) * 64 + d) * 256 + s]) = pk;
      } else {
        float* C = (float*)Cbase;
        #pragma unroll
        for (int j = 0; j < 4; ++j)
          C[(size_t)(rbase + j) * GN + col] = acc[m][n][j] + bv;
      }
    }
  }
}

// ---------------------------------------------------------------------------
// Attention: one block per (b, h, half-of-128-rows). 4 waves x 32 q-rows,
// waves fully independent. Bias gathered directly from emb[d] (800B, L1).
// ---------------------------------------------------------------------------
__device__ __forceinline__ int pidx(int row, int c) {
  return (row * 256 + c) ^ ((row & 15) << 3);
}

__global__ __launch_bounds__(256, 2) void attn_kernel(
    const unsigned short* __restrict__ qh, const unsigned short* __restrict__ kh,
    const unsigned short* __restrict__ vhT, const float* __restrict__ emb,
    const int* __restrict__ cluep, const int* __restrict__ mask,
    float* __restrict__ att_out, unsigned short* __restrict__ attn_out) {
  __shared__ unsigned short P[128 * 256];   // 64 KB exactly
  const int t = threadIdx.x;
  const int lane = t & 63, w = t >> 6;
  const int half = blockIdx.x, h = blockIdx.y, b = blockIdx.z;
  const int rows0 = half * 128;
  const int wrow = w * 32;
  const int lg = lane >> 4, lr = lane & 15;
  const float scale = 0.125f;
  const int clue = cluep[0];

  bf16x8 qf[2][2];
  #pragma unroll
  for (int m = 0; m < 2; ++m)
    #pragma unroll
    for (int ks = 0; ks < 2; ++ks)
      qf[m][ks] = *reinterpret_cast<const bf16x8*>(
          qh + (size_t)(b * 256 + rows0 + wrow + m * 16 + lr) * 1024 + h * 64 + ks * 32 + lg * 8);

  int rowm[2][4];
  #pragma unroll
  for (int m = 0; m < 2; ++m)
    #pragma unroll
    for (int j = 0; j < 4; ++j)
      rowm[m][j] = mask[b * 256 + rows0 + wrow + m * 16 + lg * 4 + j];

  float psum[2][4] = {};

  for (int ct = 0; ct < 4; ++ct) {       // 64-column chunks
    f32x4 acc[2][4] = {};
    #pragma unroll
    for (int ks = 0; ks < 2; ++ks) {
      bf16x8 kf[4];
      #pragma unroll
      for (int n = 0; n < 4; ++n)
        kf[n] = *reinterpret_cast<const bf16x8*>(
            kh + (size_t)(b * 256 + ct * 64 + n * 16 + lr) * 1024 + h * 64 + ks * 32 + lg * 8);
      __builtin_amdgcn_s_setprio(1);
      #pragma unroll
      for (int m = 0; m < 2; ++m)
        #pragma unroll
        for (int n = 0; n < 4; ++n)
          acc[m][n] = __builtin_amdgcn_mfma_f32_16x16x32_bf16(qf[m][ks], kf[n], acc[m][n], 0, 0, 0);
      __builtin_amdgcn_s_setprio(0);
    }
    #pragma unroll
    for (int n = 0; n < 4; ++n) {
      const int c = ct * 64 + n * 16 + lr;
      const int colm = mask[b * 256 + c];
      const bool cside = c >= clue;
      #pragma unroll
      for (int m = 0; m < 2; ++m) {
        const int rloc = wrow + m * 16 + lg * 4;
        #pragma unroll
        for (int j = 0; j < 4; ++j) {
          const int i = rows0 + rloc + j;
          const int d = (((i >= clue)) == cside) ? (i > c ? i - c : c - i) : 1;
          float s = acc[m][n][j] * scale + emb[d];
          float p = (rowm[m][j] & colm) ? __expf(s) : 0.f;
          psum[m][j] += p;
          P[pidx(rloc + j, c)] = f2bf(p);
        }
      }
    }
  }

  // row-sum butterfly over the 16 column-lanes
  #pragma unroll
  for (int off = 1; off < 16; off <<= 1)
    #pragma unroll
    for (int m = 0; m < 2; ++m)
      #pragma unroll
      for (int j = 0; j < 4; ++j)
        psum[m][j] += __shfl_xor(psum[m][j], off);

  // Phase 2: att output (normalized; masked rows give inv=0)
  const size_t att_base = (size_t)(b * 16 + h) * 65536;
  #pragma unroll
  for (int it = 0; it < 16; ++it) {
    const int m2 = it >> 3;
    const int lg2 = (it >> 1) & 3;
    const int b0 = (2 * it) & 3;
    const float s0 = __shfl(psum[m2][b0], lg2 * 16);
    const float s1 = __shfl(psum[m2][b0 + 1], lg2 * 16);
    const int rloc = wrow + it * 2 + (lane >> 5);
    const int rabs = rows0 + rloc;
    const float sum = (lane >= 32) ? s1 : s0;
    const float inv = sum > 0.f ? 1.f / sum : 0.f;
    const int c8 = (lane & 31) * 8;
    bf16x8 pv = *reinterpret_cast<const bf16x8*>(&P[pidx(rloc, c8)]);
    float4 o1, o2;
    o1.x = (float)pv[0] * inv; o1.y = (float)pv[1] * inv;
    o1.z = (float)pv[2] * inv; o1.w = (float)pv[3] * inv;
    o2.x = (float)pv[4] * inv; o2.y = (float)pv[5] * inv;
    o2.z = (float)pv[6] * inv; o2.w = (float)pv[7] * inv;
    *reinterpret_cast<float4*>(&att_out[att_base + (size_t)rabs * 256 + c8]) = o1;
    *reinterpret_cast<float4*>(&att_out[att_base + (size_t)rabs * 256 + c8 + 4]) = o2;
  }

  // Phase 3: O = P @ V
  f32x4 oacc[2][4] = {};
  for (int ks = 0; ks < 8; ++ks) {
    bf16x8 pa[2], vf[4];
    #pragma unroll
    for (int m = 0; m < 2; ++m)
      pa[m] = *reinterpret_cast<const bf16x8*>(&P[pidx(wrow + m * 16 + lr, ks * 32 + lg * 8)]);
    #pragma unroll
    for (int dn = 0; dn < 4; ++dn)
      vf[dn] = *reinterpret_cast<const bf16x8*>(
          vhT + (size_t)((b * 16 + h) * 64 + dn * 16 + lr) * 256 + ks * 32 + lg * 8);
    __builtin_amdgcn_s_setprio(1);
    #pragma unroll
    for (int m = 0; m < 2; ++m)
      #pragma unroll
      for (int dn = 0; dn < 4; ++dn)
        oacc[m][dn] = __builtin_amdgcn_mfma_f32_16x16x32_bf16(pa[m], vf[dn], oacc[m][dn], 0, 0, 0);
    __builtin_amdgcn_s_setprio(0);
  }
  #pragma unroll
  for (int m = 0; m < 2; ++m) {
    #pragma unroll
    for (int dn = 0; dn < 4; ++dn) {
      #pragma unroll
      for (int j = 0; j < 4; ++j) {
        const int rloc = wrow + m * 16 + lg * 4 + j;
        const float sum = psum[m][j];
        const float inv = sum > 0.f ? 1.f / sum : 0.f;
        attn_out[(size_t)(b * 256 + rows0 + rloc) * 1024 + h * 64 + dn * 16 + lr] =
            f2bf(oacc[m][dn][j] * inv);
      }
    }
  }
}

// ---------------------------------------------------------------------------
extern "C" void kernel_launch(void* const* d_in, const int* in_sizes, int n_in,
                              void* d_out, int out_size, void* d_ws, size_t ws_size,
                              hipStream_t stream) {
  (void)in_sizes; (void)n_in; (void)out_size; (void)ws_size;
  const float* q    = (const float*)d_in[0];
  const float* k    = (const float*)d_in[1];
  const float* v    = (const float*)d_in[2];
  const int*   clue = (const int*)d_in[3];
  const int*   mask = (const int*)d_in[4];
  const float* Wq   = (const float*)d_in[5];
  const float* bq   = (const float*)d_in[6];
  const float* Wk   = (const float*)d_in[7];
  const float* bk   = (const float*)d_in[8];
  const float* Wv   = (const float*)d_in[9];
  const float* bv   = (const float*)d_in[10];
  const float* Wo   = (const float*)d_in[11];
  const float* bo   = (const float*)d_in[12];
  const float* emb  = (const float*)d_in[13];

  char* ws = (char*)d_ws;
  unsigned short* WT   = (unsigned short*)(ws);                 // 4 x 2M ushorts = 16MB
  size_t off = 16u << 20;
  unsigned short* qh   = (unsigned short*)(ws + off); off += (16u << 20);
  unsigned short* kh   = (unsigned short*)(ws + off); off += (16u << 20);
  unsigned short* vhT  = (unsigned short*)(ws + off); off += (16u << 20);
  unsigned short* aout = (unsigned short*)(ws + off); off += (16u << 20);
  unsigned short* qkvb = (unsigned short*)(ws + off);           // qb,kb,vb contiguous 48MB
  (void)kh; (void)vhT;

  float* out  = (float*)d_out;
  float* embo = out + 8388608;     // [B,H,S,S]
  float* atto = out + 41943040;    // [B,H,S,S]

  prep_kernel<<<11264, 256, 0, stream>>>(q, k, v, Wq, Wk, Wv, Wo, emb, clue,
                                         embo, qkvb, WT);
  // MEASUREMENT: duplicated QKV GEMM (idempotent — writes identical bytes).
  // QKV_time ≈ dur_us(this round) − 572.7.
  gemm_fused<<<dim3(8, 64, 3), 256, 0, stream>>>(qkvb, WT, bq, bk, bv, qh, 0);
  gemm_fused<<<dim3(8, 64, 3), 256, 0, stream>>>(qkvb, WT, bq, bk, bv, qh, 0);
  attn_kernel<<<dim3(2, 16, 32), 256, 0, stream>>>(qh, kh, vhT, emb, clue, mask, atto, aout);
  gemm_fused<<<dim3(8, 64, 1), 256, 0, stream>>>(aout, WT + 3 * 2097152, bo, bo, bo, out, 2);
}

// Round 13
// 587.713 us; speedup vs baseline: 1.0836x; 1.0836x over previous
//
#include <hip/hip_runtime.h>
#include <stdint.h>

// ---------------------------------------------------------------------------
// Problem constants: B=32, S=256, HID=1024, HEADS=16, DK=64, CLUE(runtime)=64
// ---------------------------------------------------------------------------
typedef __bf16 bf16_t;
typedef bf16_t bf16x8 __attribute__((ext_vector_type(8)));
typedef float f32x4 __attribute__((ext_vector_type(4)));

__device__ __forceinline__ unsigned short f2bf(float f) {
  __bf16 h = (__bf16)f;            // RNE, compiles to v_cvt
  unsigned short u;
  __builtin_memcpy(&u, &h, 2);
  return u;
}

__device__ __forceinline__ void gload16(const unsigned short* g, unsigned short* l) {
  auto gp = (const __attribute__((address_space(1))) unsigned short*)(g);
  auto lp = (__attribute__((address_space(3))) unsigned short*)(l);
  __builtin_amdgcn_global_load_lds(gp, lp, 16, 0, 0);   // 16B/lane, dest = base + lane*16
}

// d(i,j): |i-j| when i,j on the same side of clue, else 1  (fp matrix of ref)
__device__ __forceinline__ int relidx(int i, int j, int clue) {
  return ((i >= clue) == (j >= clue)) ? (i > j ? i - j : j - i) : 1;
}

// ---------------------------------------------------------------------------
// prep kernel — blockIdx partition:
//   [0,3072):     q/k/v f32 -> bf16 (1024 blocks each)
//   [3072,7168):  Wq/Wk/Wv/Wo [K][N] f32 -> WT [N][K] bf16 (1024 blocks each)
// (embo broadcast moved into gemm_fused z=3 to overlap with QKV MFMA)
// ---------------------------------------------------------------------------
__global__ __launch_bounds__(256) void prep_kernel(
    const float* __restrict__ q, const float* __restrict__ k, const float* __restrict__ v,
    const float* __restrict__ Wq, const float* __restrict__ Wk,
    const float* __restrict__ Wv, const float* __restrict__ Wo,
    unsigned short* __restrict__ qkvb, unsigned short* __restrict__ WT) {
  __shared__ float tile[32][33];
  const int bid = blockIdx.x, tid = threadIdx.x;

  if (bid < 3072) {
    const int which = bid >> 10, lb = bid & 1023;
    const float* in_ = which == 0 ? q : which == 1 ? k : v;
    unsigned short* out_ = qkvb + (size_t)which * 8388608;
    for (int i = lb * 256 + tid; i < 1048576; i += 262144) {   // 8 elems/iter
      float4 a = reinterpret_cast<const float4*>(in_)[2 * i];
      float4 b = reinterpret_cast<const float4*>(in_)[2 * i + 1];
      ushort4 p, qq;
      p.x = f2bf(a.x); p.y = f2bf(a.y); p.z = f2bf(a.z); p.w = f2bf(a.w);
      qq.x = f2bf(b.x); qq.y = f2bf(b.y); qq.z = f2bf(b.z); qq.w = f2bf(b.w);
      reinterpret_cast<ushort4*>(out_)[2 * i] = p;
      reinterpret_cast<ushort4*>(out_)[2 * i + 1] = qq;
    }
  } else {
    const int local = bid - 3072;
    const int which = local >> 10, wl = local & 1023;
    const float* in_ = which == 0 ? Wq : which == 1 ? Wk : which == 2 ? Wv : Wo;
    unsigned short* out_ = WT + (size_t)which * 2097152;
    const int tx = tid & 31, ty = tid >> 5;
    const int k0 = (wl & 31) * 32, n0 = (wl >> 5) * 32;
    #pragma unroll
    for (int p = 0; p < 4; ++p)
      tile[ty + p * 8][tx] = in_[(size_t)(k0 + ty + p * 8) * 1024 + n0 + tx];
    __syncthreads();
    #pragma unroll
    for (int p = 0; p < 4; ++p)
      out_[(size_t)(n0 + ty + p * 8) * 1024 + k0 + tx] = f2bf(tile[tx][ty + p * 8]);
  }
}

// ---------------------------------------------------------------------------
// GEMM: C[8192][1024] = A(bf16) @ BT^T + bvec.  128x128 tile, BK=64, 4 waves,
// mfma_f32_16x16x32_bf16, global_load_lds(16) staging with pre-swizzled global
// source (linear LDS dest, XOR on read side — rule #21 both-sides).
// grid.z: 0..2 = q/k/v slices (contiguous A/BT/C bases); z==3 (QKV launch
// only) = embo broadcast blocks — pure streaming writes that overlap with the
// compute-bound GEMM blocks on the same launch. mode==2: O-projection (f32 C).
// z==2 with mode==0: vhT[b,h,d,s] transposed epilogue.
// ---------------------------------------------------------------------------
constexpr int GK = 1024, GN = 1024;

__global__ __launch_bounds__(256, 3) void gemm_fused(
    const unsigned short* __restrict__ Abase, const unsigned short* __restrict__ BTbase,
    const float* __restrict__ b0, const float* __restrict__ b1, const float* __restrict__ b2,
    void* __restrict__ Cbase, int mode,
    const float* __restrict__ emb, const int* __restrict__ cluep,
    float* __restrict__ embo) {
  __shared__ unsigned short Alds[128 * 64];   // 16 KB, linear
  __shared__ unsigned short Blds[128 * 64];
  const int t = threadIdx.x;
  const int zz = blockIdx.z;

  if (zz == 3) {
    // embo broadcast: one [S,S] tile (65536 floats) per block, 512 blocks.
    const int tb = blockIdx.y * 8 + blockIdx.x;      // tile index in [0,512)
    const int clue = cluep[0];
    float4* o4 = reinterpret_cast<float4*>(embo);
    #pragma unroll
    for (int it = 0; it < 64; ++it) {
      const int lpos = it * 256 + t;                 // float4 within tile
      const int fpos = lpos * 4;
      const int i = fpos >> 8, j0 = fpos & 255;
      float4 r;
      r.x = emb[relidx(i, j0 + 0, clue)];
      r.y = emb[relidx(i, j0 + 1, clue)];
      r.z = emb[relidx(i, j0 + 2, clue)];
      r.w = emb[relidx(i, j0 + 3, clue)];
      o4[(size_t)tb * 16384 + lpos] = r;
    }
    return;
  }

  const int lane = t & 63;
  const int w = t >> 6;
  const int wr = (w >> 1) * 64;
  const int wc = (w & 1) * 64;
  const int m0 = blockIdx.y * 128;
  const int n0 = blockIdx.x * 128;
  const int lg = lane >> 4;
  const int lr = lane & 15;

  const unsigned short* A  = Abase + (size_t)zz * 8388608;
  const unsigned short* BT = BTbase + (size_t)zz * 2097152;
  const float* bvec = zz == 0 ? b0 : zz == 1 ? b1 : b2;

  const int srow = w * 32 + (lane >> 3);            // + i*8
  const int gch  = (lane & 7) ^ ((lane >> 3) & 7);  // swizzled source chunk

  f32x4 acc[4][4] = {};

  for (int k0 = 0; k0 < GK; k0 += 64) {
    #pragma unroll
    for (int i = 0; i < 4; ++i) {
      gload16(A  + (size_t)(m0 + srow + i * 8) * GK + k0 + gch * 8,
              &Alds[(w * 32 + i * 8) * 64]);
      gload16(BT + (size_t)(n0 + srow + i * 8) * GK + k0 + gch * 8,
              &Blds[(w * 32 + i * 8) * 64]);
    }
    __syncthreads();
    #pragma unroll
    for (int ks = 0; ks < 2; ++ks) {
      bf16x8 af[4], bfr[4];
      #pragma unroll
      for (int m = 0; m < 4; ++m) {
        const int r = wr + m * 16 + lr;
        const int cc = (ks * 4 + lg) ^ (lr & 7);
        af[m] = *reinterpret_cast<const bf16x8*>(&Alds[r * 64 + cc * 8]);
      }
      #pragma unroll
      for (int n = 0; n < 4; ++n) {
        const int r = wc + n * 16 + lr;
        const int cc = (ks * 4 + lg) ^ (lr & 7);
        bfr[n] = *reinterpret_cast<const bf16x8*>(&Blds[r * 64 + cc * 8]);
      }
      __builtin_amdgcn_s_setprio(1);
      #pragma unroll
      for (int m = 0; m < 4; ++m) {
        #pragma unroll
        for (int n = 0; n < 4; ++n)
          acc[m][n] = __builtin_amdgcn_mfma_f32_16x16x32_bf16(af[m], bfr[n], acc[m][n], 0, 0, 0);
      }
      __builtin_amdgcn_s_setprio(0);
    }
    __syncthreads();
  }

  const int omode = (mode == 2) ? 2 : (zz == 2 ? 1 : 0);
  #pragma unroll
  for (int m = 0; m < 4; ++m) {
    #pragma unroll
    for (int n = 0; n < 4; ++n) {
      const int col = n0 + wc + n * 16 + lr;
      const float bv = bvec[col];
      const int rbase = m0 + wr + m * 16 + lg * 4;
      if (omode == 0) {
        unsigned short* C = (unsigned short*)Cbase + (size_t)zz * 8388608;
        #pragma unroll
        for (int j = 0; j < 4; ++j)
          C[(size_t)(rbase + j) * GN + col] = f2bf(acc[m][n][j] + bv);
      } else if (omode == 1) {
        unsigned short* C = (unsigned short*)Cbase + (size_t)zz * 8388608;  // vhT
        const int b = rbase >> 8, s = rbase & 255;
        const int h = col >> 6, d = col & 63;
        ushort4 pk;
        pk.x = f2bf(acc[m][n][0] + bv);
        pk.y = f2bf(acc[m][n][1] + bv);
        pk.z = f2bf(acc[m][n][2] + bv);
        pk.w = f2bf(acc[m][n][3] + bv);
        *reinterpret_cast<ushort4*>(&C[(size_t)((b * 16 + h) * 64 + d) * 256 + s]) = pk;
      } else {
        float* C = (float*)Cbase;
        #pragma unroll
        for (int j = 0; j < 4; ++j)
          C[(size_t)(rbase + j) * GN + col] = acc[m][n][j] + bv;
      }
    }
  }
}

// ---------------------------------------------------------------------------
// Attention: one block per (b, h, half-of-128-rows). 4 waves x 32 q-rows,
// waves fully independent. Bias gathered directly from emb[d] (800B, L1).
// ---------------------------------------------------------------------------
__device__ __forceinline__ int pidx(int row, int c) {
  return (row * 256 + c) ^ ((row & 15) << 3);
}

__global__ __launch_bounds__(256, 2) void attn_kernel(
    const unsigned short* __restrict__ qh, const unsigned short* __restrict__ kh,
    const unsigned short* __restrict__ vhT, const float* __restrict__ emb,
    const int* __restrict__ cluep, const int* __restrict__ mask,
    float* __restrict__ att_out, unsigned short* __restrict__ attn_out) {
  __shared__ unsigned short P[128 * 256];   // 64 KB exactly
  const int t = threadIdx.x;
  const int lane = t & 63, w = t >> 6;
  const int half = blockIdx.x, h = blockIdx.y, b = blockIdx.z;
  const int rows0 = half * 128;
  const int wrow = w * 32;
  const int lg = lane >> 4, lr = lane & 15;
  const float scale = 0.125f;
  const int clue = cluep[0];

  bf16x8 qf[2][2];
  #pragma unroll
  for (int m = 0; m < 2; ++m)
    #pragma unroll
    for (int ks = 0; ks < 2; ++ks)
      qf[m][ks] = *reinterpret_cast<const bf16x8*>(
          qh + (size_t)(b * 256 + rows0 + wrow + m * 16 + lr) * 1024 + h * 64 + ks * 32 + lg * 8);

  int rowm[2][4];
  #pragma unroll
  for (int m = 0; m < 2; ++m)
    #pragma unroll
    for (int j = 0; j < 4; ++j)
      rowm[m][j] = mask[b * 256 + rows0 + wrow + m * 16 + lg * 4 + j];

  float psum[2][4] = {};

  for (int ct = 0; ct < 4; ++ct) {       // 64-column chunks
    f32x4 acc[2][4] = {};
    #pragma unroll
    for (int ks = 0; ks < 2; ++ks) {
      bf16x8 kf[4];
      #pragma unroll
      for (int n = 0; n < 4; ++n)
        kf[n] = *reinterpret_cast<const bf16x8*>(
            kh + (size_t)(b * 256 + ct * 64 + n * 16 + lr) * 1024 + h * 64 + ks * 32 + lg * 8);
      __builtin_amdgcn_s_setprio(1);
      #pragma unroll
      for (int m = 0; m < 2; ++m)
        #pragma unroll
        for (int n = 0; n < 4; ++n)
          acc[m][n] = __builtin_amdgcn_mfma_f32_16x16x32_bf16(qf[m][ks], kf[n], acc[m][n], 0, 0, 0);
      __builtin_amdgcn_s_setprio(0);
    }
    #pragma unroll
    for (int n = 0; n < 4; ++n) {
      const int c = ct * 64 + n * 16 + lr;
      const int colm = mask[b * 256 + c];
      const bool cside = c >= clue;
      #pragma unroll
      for (int m = 0; m < 2; ++m) {
        const int rloc = wrow + m * 16 + lg * 4;
        #pragma unroll
        for (int j = 0; j < 4; ++j) {
          const int i = rows0 + rloc + j;
          const int d = (((i >= clue)) == cside) ? (i > c ? i - c : c - i) : 1;
          float s = acc[m][n][j] * scale + emb[d];
          float p = (rowm[m][j] & colm) ? __expf(s) : 0.f;
          psum[m][j] += p;
          P[pidx(rloc + j, c)] = f2bf(p);
        }
      }
    }
  }

  // row-sum butterfly over the 16 column-lanes
  #pragma unroll
  for (int off = 1; off < 16; off <<= 1)
    #pragma unroll
    for (int m = 0; m < 2; ++m)
      #pragma unroll
      for (int j = 0; j < 4; ++j)
        psum[m][j] += __shfl_xor(psum[m][j], off);

  // Phase 2: att output (normalized; masked rows give inv=0)
  const size_t att_base = (size_t)(b * 16 + h) * 65536;
  #pragma unroll
  for (int it = 0; it < 16; ++it) {
    const int m2 = it >> 3;
    const int lg2 = (it >> 1) & 3;
    const int b0 = (2 * it) & 3;
    const float s0 = __shfl(psum[m2][b0], lg2 * 16);
    const float s1 = __shfl(psum[m2][b0 + 1], lg2 * 16);
    const int rloc = wrow + it * 2 + (lane >> 5);
    const int rabs = rows0 + rloc;
    const float sum = (lane >= 32) ? s1 : s0;
    const float inv = sum > 0.f ? 1.f / sum : 0.f;
    const int c8 = (lane & 31) * 8;
    bf16x8 pv = *reinterpret_cast<const bf16x8*>(&P[pidx(rloc, c8)]);
    float4 o1, o2;
    o1.x = (float)pv[0] * inv; o1.y = (float)pv[1] * inv;
    o1.z = (float)pv[2] * inv; o1.w = (float)pv[3] * inv;
    o2.x = (float)pv[4] * inv; o2.y = (float)pv[5] * inv;
    o2.z = (float)pv[6] * inv; o2.w = (float)pv[7] * inv;
    *reinterpret_cast<float4*>(&att_out[att_base + (size_t)rabs * 256 + c8]) = o1;
    *reinterpret_cast<float4*>(&att_out[att_base + (size_t)rabs * 256 + c8 + 4]) = o2;
  }

  // Phase 3: O = P @ V
  f32x4 oacc[2][4] = {};
  for (int ks = 0; ks < 8; ++ks) {
    bf16x8 pa[2], vf[4];
    #pragma unroll
    for (int m = 0; m < 2; ++m)
      pa[m] = *reinterpret_cast<const bf16x8*>(&P[pidx(wrow + m * 16 + lr, ks * 32 + lg * 8)]);
    #pragma unroll
    for (int dn = 0; dn < 4; ++dn)
      vf[dn] = *reinterpret_cast<const bf16x8*>(
          vhT + (size_t)((b * 16 + h) * 64 + dn * 16 + lr) * 256 + ks * 32 + lg * 8);
    __builtin_amdgcn_s_setprio(1);
    #pragma unroll
    for (int m = 0; m < 2; ++m)
      #pragma unroll
      for (int dn = 0; dn < 4; ++dn)
        oacc[m][dn] = __builtin_amdgcn_mfma_f32_16x16x32_bf16(pa[m], vf[dn], oacc[m][dn], 0, 0, 0);
    __builtin_amdgcn_s_setprio(0);
  }
  #pragma unroll
  for (int m = 0; m < 2; ++m) {
    #pragma unroll
    for (int dn = 0; dn < 4; ++dn) {
      #pragma unroll
      for (int j = 0; j < 4; ++j) {
        const int rloc = wrow + m * 16 + lg * 4 + j;
        const float sum = psum[m][j];
        const float inv = sum > 0.f ? 1.f / sum : 0.f;
        attn_out[(size_t)(b * 256 + rows0 + rloc) * 1024 + h * 64 + dn * 16 + lr] =
            f2bf(oacc[m][dn][j] * inv);
      }
    }
  }
}

// ---------------------------------------------------------------------------
extern "C" void kernel_launch(void* const* d_in, const int* in_sizes, int n_in,
                              void* d_out, int out_size, void* d_ws, size_t ws_size,
                              hipStream_t stream) {
  (void)in_sizes; (void)n_in; (void)out_size; (void)ws_size;
  const float* q    = (const float*)d_in[0];
  const float* k    = (const float*)d_in[1];
  const float* v    = (const float*)d_in[2];
  const int*   clue = (const int*)d_in[3];
  const int*   mask = (const int*)d_in[4];
  const float* Wq   = (const float*)d_in[5];
  const float* bq   = (const float*)d_in[6];
  const float* Wk   = (const float*)d_in[7];
  const float* bk   = (const float*)d_in[8];
  const float* Wv   = (const float*)d_in[9];
  const float* bv   = (const float*)d_in[10];
  const float* Wo   = (const float*)d_in[11];
  const float* bo   = (const float*)d_in[12];
  const float* emb  = (const float*)d_in[13];

  char* ws = (char*)d_ws;
  unsigned short* WT   = (unsigned short*)(ws);                 // 4 x 2M ushorts = 16MB
  size_t off = 16u << 20;
  unsigned short* qh   = (unsigned short*)(ws + off); off += (16u << 20);
  unsigned short* kh   = (unsigned short*)(ws + off); off += (16u << 20);
  unsigned short* vhT  = (unsigned short*)(ws + off); off += (16u << 20);
  unsigned short* aout = (unsigned short*)(ws + off); off += (16u << 20);
  unsigned short* qkvb = (unsigned short*)(ws + off);           // qb,kb,vb contiguous 48MB
  (void)kh; (void)vhT;

  float* out  = (float*)d_out;
  float* embo = out + 8388608;     // [B,H,S,S]
  float* atto = out + 41943040;    // [B,H,S,S]

  prep_kernel<<<7168, 256, 0, stream>>>(q, k, v, Wq, Wk, Wv, Wo, qkvb, WT);
  // z=0..2: q/k/v projections; z=3: embo broadcast (overlaps with GEMM MFMA)
  gemm_fused<<<dim3(8, 64, 4), 256, 0, stream>>>(qkvb, WT, bq, bk, bv, qh, 0,
                                                 emb, clue, embo);
  attn_kernel<<<dim3(2, 16, 32), 256, 0, stream>>>(qh, kh, vhT, emb, clue, mask, atto, aout);
  gemm_fused<<<dim3(8, 64, 1), 256, 0, stream>>>(aout, WT + 3 * 2097152, bo, bo, bo, out, 2,
                                                 emb, clue, embo);
}

// Round 14
// 567.869 us; speedup vs baseline: 1.1215x; 1.0349x over previous
//
#include <hip/hip_runtime.h>
#include <stdint.h>

// ---------------------------------------------------------------------------
// Problem constants: B=32, S=256, HID=1024, HEADS=16, DK=64, CLUE(runtime)=64
// ---------------------------------------------------------------------------
typedef __bf16 bf16_t;
typedef bf16_t bf16x8 __attribute__((ext_vector_type(8)));
typedef float f32x4 __attribute__((ext_vector_type(4)));

__device__ __forceinline__ unsigned short f2bf(float f) {
  __bf16 h = (__bf16)f;            // RNE, compiles to v_cvt
  unsigned short u;
  __builtin_memcpy(&u, &h, 2);
  return u;
}

__device__ __forceinline__ void gload16(const unsigned short* g, unsigned short* l) {
  auto gp = (const __attribute__((address_space(1))) unsigned short*)(g);
  auto lp = (__attribute__((address_space(3))) unsigned short*)(l);
  __builtin_amdgcn_global_load_lds(gp, lp, 16, 0, 0);   // 16B/lane, dest = base + lane*16
}

// ---------------------------------------------------------------------------
// prep kernel — blockIdx partition:
//   [0,3072):     q/k/v f32 -> bf16 (1024 blocks each)
//   [3072,7168):  Wq/Wk/Wv/Wo [K][N] f32 -> WT [N][K] bf16 (1024 blocks each)
// (embedding output is written by attn_kernel, which computes bias anyway)
// ---------------------------------------------------------------------------
__global__ __launch_bounds__(256) void prep_kernel(
    const float* __restrict__ q, const float* __restrict__ k, const float* __restrict__ v,
    const float* __restrict__ Wq, const float* __restrict__ Wk,
    const float* __restrict__ Wv, const float* __restrict__ Wo,
    unsigned short* __restrict__ qkvb, unsigned short* __restrict__ WT) {
  __shared__ float tile[32][33];
  const int bid = blockIdx.x, tid = threadIdx.x;

  if (bid < 3072) {
    const int which = bid >> 10, lb = bid & 1023;
    const float* in_ = which == 0 ? q : which == 1 ? k : v;
    unsigned short* out_ = qkvb + (size_t)which * 8388608;
    for (int i = lb * 256 + tid; i < 1048576; i += 262144) {   // 8 elems/iter
      float4 a = reinterpret_cast<const float4*>(in_)[2 * i];
      float4 b = reinterpret_cast<const float4*>(in_)[2 * i + 1];
      ushort4 p, qq;
      p.x = f2bf(a.x); p.y = f2bf(a.y); p.z = f2bf(a.z); p.w = f2bf(a.w);
      qq.x = f2bf(b.x); qq.y = f2bf(b.y); qq.z = f2bf(b.z); qq.w = f2bf(b.w);
      reinterpret_cast<ushort4*>(out_)[2 * i] = p;
      reinterpret_cast<ushort4*>(out_)[2 * i + 1] = qq;
    }
  } else {
    const int local = bid - 3072;
    const int which = local >> 10, wl = local & 1023;
    const float* in_ = which == 0 ? Wq : which == 1 ? Wk : which == 2 ? Wv : Wo;
    unsigned short* out_ = WT + (size_t)which * 2097152;
    const int tx = tid & 31, ty = tid >> 5;
    const int k0 = (wl & 31) * 32, n0 = (wl >> 5) * 32;
    #pragma unroll
    for (int p = 0; p < 4; ++p)
      tile[ty + p * 8][tx] = in_[(size_t)(k0 + ty + p * 8) * 1024 + n0 + tx];
    __syncthreads();
    #pragma unroll
    for (int p = 0; p < 4; ++p)
      out_[(size_t)(n0 + ty + p * 8) * 1024 + k0 + tx] = f2bf(tile[tx][ty + p * 8]);
  }
}

// ---------------------------------------------------------------------------
// GEMM: C[8192][1024] = A(bf16) @ BT^T + bvec.  128x128 tile, BK=64, 4 waves,
// mfma_f32_16x16x32_bf16, global_load_lds(16) staging with pre-swizzled global
// source (linear LDS dest, XOR on read side — rule #21 both-sides).
// grid.z selects q/k/v slice. mode==2: O-projection (f32 C). z==2 with
// mode==0: vhT[b,h,d,s] transposed epilogue.
// ---------------------------------------------------------------------------
constexpr int GK = 1024, GN = 1024;

__global__ __launch_bounds__(256, 3) void gemm_fused(
    const unsigned short* __restrict__ Abase, const unsigned short* __restrict__ BTbase,
    const float* __restrict__ b0, const float* __restrict__ b1, const float* __restrict__ b2,
    void* __restrict__ Cbase, int mode) {
  __shared__ unsigned short Alds[128 * 64];   // 16 KB, linear
  __shared__ unsigned short Blds[128 * 64];
  const int t = threadIdx.x;
  const int lane = t & 63;
  const int w = t >> 6;
  const int wr = (w >> 1) * 64;
  const int wc = (w & 1) * 64;
  const int m0 = blockIdx.y * 128;
  const int n0 = blockIdx.x * 128;
  const int zz = blockIdx.z;
  const int lg = lane >> 4;
  const int lr = lane & 15;

  const unsigned short* A  = Abase + (size_t)zz * 8388608;
  const unsigned short* BT = BTbase + (size_t)zz * 2097152;
  const float* bvec = zz == 0 ? b0 : zz == 1 ? b1 : b2;

  const int srow = w * 32 + (lane >> 3);            // + i*8
  const int gch  = (lane & 7) ^ ((lane >> 3) & 7);  // swizzled source chunk

  f32x4 acc[4][4] = {};

  for (int k0 = 0; k0 < GK; k0 += 64) {
    #pragma unroll
    for (int i = 0; i < 4; ++i) {
      gload16(A  + (size_t)(m0 + srow + i * 8) * GK + k0 + gch * 8,
              &Alds[(w * 32 + i * 8) * 64]);
      gload16(BT + (size_t)(n0 + srow + i * 8) * GK + k0 + gch * 8,
              &Blds[(w * 32 + i * 8) * 64]);
    }
    __syncthreads();
    #pragma unroll
    for (int ks = 0; ks < 2; ++ks) {
      bf16x8 af[4], bfr[4];
      #pragma unroll
      for (int m = 0; m < 4; ++m) {
        const int r = wr + m * 16 + lr;
        const int cc = (ks * 4 + lg) ^ (lr & 7);
        af[m] = *reinterpret_cast<const bf16x8*>(&Alds[r * 64 + cc * 8]);
      }
      #pragma unroll
      for (int n = 0; n < 4; ++n) {
        const int r = wc + n * 16 + lr;
        const int cc = (ks * 4 + lg) ^ (lr & 7);
        bfr[n] = *reinterpret_cast<const bf16x8*>(&Blds[r * 64 + cc * 8]);
      }
      __builtin_amdgcn_s_setprio(1);
      #pragma unroll
      for (int m = 0; m < 4; ++m) {
        #pragma unroll
        for (int n = 0; n < 4; ++n)
          acc[m][n] = __builtin_amdgcn_mfma_f32_16x16x32_bf16(af[m], bfr[n], acc[m][n], 0, 0, 0);
      }
      __builtin_amdgcn_s_setprio(0);
    }
    __syncthreads();
  }

  const int omode = (mode == 2) ? 2 : (zz == 2 ? 1 : 0);
  #pragma unroll
  for (int m = 0; m < 4; ++m) {
    #pragma unroll
    for (int n = 0; n < 4; ++n) {
      const int col = n0 + wc + n * 16 + lr;
      const float bv = bvec[col];
      const int rbase = m0 + wr + m * 16 + lg * 4;
      if (omode == 0) {
        unsigned short* C = (unsigned short*)Cbase + (size_t)zz * 8388608;
        #pragma unroll
        for (int j = 0; j < 4; ++j)
          C[(size_t)(rbase + j) * GN + col] = f2bf(acc[m][n][j] + bv);
      } else if (omode == 1) {
        unsigned short* C = (unsigned short*)Cbase + (size_t)zz * 8388608;  // vhT
        const int b = rbase >> 8, s = rbase & 255;
        const int h = col >> 6, d = col & 63;
        ushort4 pk;
        pk.x = f2bf(acc[m][n][0] + bv);
        pk.y = f2bf(acc[m][n][1] + bv);
        pk.z = f2bf(acc[m][n][2] + bv);
        pk.w = f2bf(acc[m][n][3] + bv);
        *reinterpret_cast<ushort4*>(&C[(size_t)((b * 16 + h) * 64 + d) * 256 + s]) = pk;
      } else {
        float* C = (float*)Cbase;
        #pragma unroll
        for (int j = 0; j < 4; ++j)
          C[(size_t)(rbase + j) * GN + col] = acc[m][n][j] + bv;
      }
    }
  }
}

// ---------------------------------------------------------------------------
// Attention: one block per (b, h, half-of-128-rows). 4 waves x 32 q-rows,
// waves fully independent. Bias computed from emb[d] (800B, L1) — and since
// embedding[b,h] output IS that bias tile, each block also stores its slice
// (unconditional dword stores, overlapped with MFMA phases).
// ---------------------------------------------------------------------------
__device__ __forceinline__ int pidx(int row, int c) {
  return (row * 256 + c) ^ ((row & 15) << 3);
}

__global__ __launch_bounds__(256, 2) void attn_kernel(
    const unsigned short* __restrict__ qh, const unsigned short* __restrict__ kh,
    const unsigned short* __restrict__ vhT, const float* __restrict__ emb,
    const int* __restrict__ cluep, const int* __restrict__ mask,
    float* __restrict__ emb_out, float* __restrict__ att_out,
    unsigned short* __restrict__ attn_out) {
  __shared__ unsigned short P[128 * 256];   // 64 KB exactly
  const int t = threadIdx.x;
  const int lane = t & 63, w = t >> 6;
  const int half = blockIdx.x, h = blockIdx.y, b = blockIdx.z;
  const int rows0 = half * 128;
  const int wrow = w * 32;
  const int lg = lane >> 4, lr = lane & 15;
  const float scale = 0.125f;
  const int clue = cluep[0];

  bf16x8 qf[2][2];
  #pragma unroll
  for (int m = 0; m < 2; ++m)
    #pragma unroll
    for (int ks = 0; ks < 2; ++ks)
      qf[m][ks] = *reinterpret_cast<const bf16x8*>(
          qh + (size_t)(b * 256 + rows0 + wrow + m * 16 + lr) * 1024 + h * 64 + ks * 32 + lg * 8);

  int rowm[2][4];
  #pragma unroll
  for (int m = 0; m < 2; ++m)
    #pragma unroll
    for (int j = 0; j < 4; ++j)
      rowm[m][j] = mask[b * 256 + rows0 + wrow + m * 16 + lg * 4 + j];

  const size_t bh_base = (size_t)(b * 16 + h) * 65536;
  float psum[2][4] = {};

  for (int ct = 0; ct < 4; ++ct) {       // 64-column chunks
    f32x4 acc[2][4] = {};
    #pragma unroll
    for (int ks = 0; ks < 2; ++ks) {
      bf16x8 kf[4];
      #pragma unroll
      for (int n = 0; n < 4; ++n)
        kf[n] = *reinterpret_cast<const bf16x8*>(
            kh + (size_t)(b * 256 + ct * 64 + n * 16 + lr) * 1024 + h * 64 + ks * 32 + lg * 8);
      __builtin_amdgcn_s_setprio(1);
      #pragma unroll
      for (int m = 0; m < 2; ++m)
        #pragma unroll
        for (int n = 0; n < 4; ++n)
          acc[m][n] = __builtin_amdgcn_mfma_f32_16x16x32_bf16(qf[m][ks], kf[n], acc[m][n], 0, 0, 0);
      __builtin_amdgcn_s_setprio(0);
    }
    #pragma unroll
    for (int n = 0; n < 4; ++n) {
      const int c = ct * 64 + n * 16 + lr;
      const int colm = mask[b * 256 + c];
      const bool cside = c >= clue;
      #pragma unroll
      for (int m = 0; m < 2; ++m) {
        const int rloc = wrow + m * 16 + lg * 4;
        #pragma unroll
        for (int j = 0; j < 4; ++j) {
          const int i = rows0 + rloc + j;
          const int d = (((i >= clue)) == cside) ? (i > c ? i - c : c - i) : 1;
          const float bv = emb[d];
          emb_out[bh_base + (size_t)i * 256 + c] = bv;     // embedding output
          float s = acc[m][n][j] * scale + bv;
          float p = (rowm[m][j] & colm) ? __expf(s) : 0.f;
          psum[m][j] += p;
          P[pidx(rloc + j, c)] = f2bf(p);
        }
      }
    }
  }

  // row-sum butterfly over the 16 column-lanes
  #pragma unroll
  for (int off = 1; off < 16; off <<= 1)
    #pragma unroll
    for (int m = 0; m < 2; ++m)
      #pragma unroll
      for (int j = 0; j < 4; ++j)
        psum[m][j] += __shfl_xor(psum[m][j], off);

  // Phase 2: att output (normalized; masked rows give inv=0)
  #pragma unroll
  for (int it = 0; it < 16; ++it) {
    const int m2 = it >> 3;
    const int lg2 = (it >> 1) & 3;
    const int b0 = (2 * it) & 3;
    const float s0 = __shfl(psum[m2][b0], lg2 * 16);
    const float s1 = __shfl(psum[m2][b0 + 1], lg2 * 16);
    const int rloc = wrow + it * 2 + (lane >> 5);
    const int rabs = rows0 + rloc;
    const float sum = (lane >= 32) ? s1 : s0;
    const float inv = sum > 0.f ? 1.f / sum : 0.f;
    const int c8 = (lane & 31) * 8;
    bf16x8 pv = *reinterpret_cast<const bf16x8*>(&P[pidx(rloc, c8)]);
    float4 o1, o2;
    o1.x = (float)pv[0] * inv; o1.y = (float)pv[1] * inv;
    o1.z = (float)pv[2] * inv; o1.w = (float)pv[3] * inv;
    o2.x = (float)pv[4] * inv; o2.y = (float)pv[5] * inv;
    o2.z = (float)pv[6] * inv; o2.w = (float)pv[7] * inv;
    *reinterpret_cast<float4*>(&att_out[bh_base + (size_t)rabs * 256 + c8]) = o1;
    *reinterpret_cast<float4*>(&att_out[bh_base + (size_t)rabs * 256 + c8 + 4]) = o2;
  }

  // Phase 3: O = P @ V
  f32x4 oacc[2][4] = {};
  for (int ks = 0; ks < 8; ++ks) {
    bf16x8 pa[2], vf[4];
    #pragma unroll
    for (int m = 0; m < 2; ++m)
      pa[m] = *reinterpret_cast<const bf16x8*>(&P[pidx(wrow + m * 16 + lr, ks * 32 + lg * 8)]);
    #pragma unroll
    for (int dn = 0; dn < 4; ++dn)
      vf[dn] = *reinterpret_cast<const bf16x8*>(
          vhT + (size_t)((b * 16 + h) * 64 + dn * 16 + lr) * 256 + ks * 32 + lg * 8);
    __builtin_amdgcn_s_setprio(1);
    #pragma unroll
    for (int m = 0; m < 2; ++m)
      #pragma unroll
      for (int dn = 0; dn < 4; ++dn)
        oacc[m][dn] = __builtin_amdgcn_mfma_f32_16x16x32_bf16(pa[m], vf[dn], oacc[m][dn], 0, 0, 0);
    __builtin_amdgcn_s_setprio(0);
  }
  #pragma unroll
  for (int m = 0; m < 2; ++m) {
    #pragma unroll
    for (int dn = 0; dn < 4; ++dn) {
      #pragma unroll
      for (int j = 0; j < 4; ++j) {
        const int rloc = wrow + m * 16 + lg * 4 + j;
        const float sum = psum[m][j];
        const float inv = sum > 0.f ? 1.f / sum : 0.f;
        attn_out[(size_t)(b * 256 + rows0 + rloc) * 1024 + h * 64 + dn * 16 + lr] =
            f2bf(oacc[m][dn][j] * inv);
      }
    }
  }
}

// ---------------------------------------------------------------------------
extern "C" void kernel_launch(void* const* d_in, const int* in_sizes, int n_in,
                              void* d_out, int out_size, void* d_ws, size_t ws_size,
                              hipStream_t stream) {
  (void)in_sizes; (void)n_in; (void)out_size; (void)ws_size;
  const float* q    = (const float*)d_in[0];
  const float* k    = (const float*)d_in[1];
  const float* v    = (const float*)d_in[2];
  const int*   clue = (const int*)d_in[3];
  const int*   mask = (const int*)d_in[4];
  const float* Wq   = (const float*)d_in[5];
  const float* bq   = (const float*)d_in[6];
  const float* Wk   = (const float*)d_in[7];
  const float* bk   = (const float*)d_in[8];
  const float* Wv   = (const float*)d_in[9];
  const float* bv   = (const float*)d_in[10];
  const float* Wo   = (const float*)d_in[11];
  const float* bo   = (const float*)d_in[12];
  const float* emb  = (const float*)d_in[13];

  char* ws = (char*)d_ws;
  unsigned short* WT   = (unsigned short*)(ws);                 // 4 x 2M ushorts = 16MB
  size_t off = 16u << 20;
  unsigned short* qh   = (unsigned short*)(ws + off); off += (16u << 20);
  unsigned short* kh   = (unsigned short*)(ws + off); off += (16u << 20);
  unsigned short* vhT  = (unsigned short*)(ws + off); off += (16u << 20);
  unsigned short* aout = (unsigned short*)(ws + off); off += (16u << 20);
  unsigned short* qkvb = (unsigned short*)(ws + off);           // qb,kb,vb contiguous 48MB
  (void)kh; (void)vhT;

  float* out  = (float*)d_out;
  float* embo = out + 8388608;     // [B,H,S,S]
  float* atto = out + 41943040;    // [B,H,S,S]

  prep_kernel<<<7168, 256, 0, stream>>>(q, k, v, Wq, Wk, Wv, Wo, qkvb, WT);
  gemm_fused<<<dim3(8, 64, 3), 256, 0, stream>>>(qkvb, WT, bq, bk, bv, qh, 0);
  attn_kernel<<<dim3(2, 16, 32), 256, 0, stream>>>(qh, kh, vhT, emb, clue, mask,
                                                   embo, atto, aout);
  gemm_fused<<<dim3(8, 64, 1), 256, 0, stream>>>(aout, WT + 3 * 2097152, bo, bo, bo, out, 2);
}